// Round 12
// baseline (243.349 us; speedup 1.0000x reference)
//
#include <hip/hip_runtime.h>
#include <hip/hip_bf16.h>

#define NNODE 4096

typedef __attribute__((ext_vector_type(8))) short bf16x8;
typedef __attribute__((ext_vector_type(4))) float f32x4;
typedef __attribute__((ext_vector_type(4))) unsigned short us4;
typedef __attribute__((ext_vector_type(8))) unsigned short us8;

__device__ __forceinline__ unsigned short f2bf(float x) {
  __hip_bfloat16 b = __float2bfloat16(x);
  return __builtin_bit_cast(unsigned short, b);
}
__device__ __forceinline__ float bf2f(unsigned short u) {
  unsigned int v = ((unsigned int)u) << 16;
  return __builtin_bit_cast(float, v);
}

// ---------------------------------------------------------------------------
// adj (0/1 int32) -> bitmask, one u64 per 64 columns.
// ---------------------------------------------------------------------------
__global__ __launch_bounds__(256) void packadj(
    const int* __restrict__ adj, unsigned long long* __restrict__ mask) {
  size_t wid = (size_t)blockIdx.x * 4 + (threadIdx.x >> 6);
  int v = adj[wid * 64 + (threadIdx.x & 63)];
  unsigned long long b = __ballot(v != 0);
  if ((threadIdx.x & 63) == 0) mask[wid] = b;
}

// ---------------------------------------------------------------------------
// transpose + bf16 cast: src [h][Nr][Fsrc] f32 -> dst [h][Fsrc][Nr] bf16
// (weights only)
// ---------------------------------------------------------------------------
__global__ __launch_bounds__(256) void transpose_bf16(
    const float* __restrict__ src, short* __restrict__ dst, int Nr, int Fsrc) {
  __shared__ float tile[64][68];
  const int t  = threadIdx.x;
  const int n0 = blockIdx.x * 64, o0 = blockIdx.y * 64;
  const int h  = blockIdx.z;
  const float* S = src + ((size_t)h * Nr + n0) * Fsrc + o0;
  short* D = dst + ((size_t)h * Fsrc + o0) * Nr + n0;
  const int r = t >> 2, cs = (t & 3) * 16;
  #pragma unroll
  for (int k2 = 0; k2 < 4; ++k2) {
    float4 v = *(const float4*)&S[(size_t)r * Fsrc + cs + k2 * 4];
    *(float4*)&tile[r][cs + k2 * 4] = v;
  }
  __syncthreads();
  const int o = t >> 2, ns = (t & 3) * 16;
  us8 u0, u1;
  #pragma unroll
  for (int e = 0; e < 8; ++e) u0[e] = f2bf(tile[ns + e][o]);
  #pragma unroll
  for (int e = 0; e < 8; ++e) u1[e] = f2bf(tile[ns + 8 + e][o]);
  *(us8*)&D[(size_t)o * Nr + ns]     = u0;
  *(us8*)&D[(size_t)o * Nr + ns + 8] = u1;
}

// ---------------------------------------------------------------------------
// GEMM via MFMA, bf16 A, fused transpose epilogue: hT[h][o][n] = (A@B[h])^T.
// 32x64 tile (more blocks -> better latency hiding), 4 waves (2x2),
// wave = 16i x 32o (1 A-frag x 2 B-frags), BK=64, B double-buffered.
// grid = (M/32, Nfull/64, H)
// ---------------------------------------------------------------------------
__global__ __launch_bounds__(256) void gemm_mfma(
    const short* __restrict__ A, const short* __restrict__ Wt,
    short* __restrict__ hTout, int M, int K, int Nfull) {
  __shared__ short As[32][72];   // [row][k] bf16
  const int t  = threadIdx.x;
  const int lane = t & 63;
  const int w  = t >> 6;
  const int i0 = blockIdx.x * 32;
  const int c0 = blockIdx.y * 64;
  const int h  = blockIdx.z;
  const short* Bh = Wt + ((size_t)h * Nfull + c0) * K;
  short*       Hh = hTout + (size_t)h * Nfull * M;

  const int R0 = (w >> 1) * 16;
  const int C0 = (w & 1) * 32;
  const int lr = lane & 15;
  const int lk = lane >> 4;

  const int arow = t >> 3;         // 0..31
  const int aseg = (t & 7) * 8;    // 0..56

  f32x4 acc[2] = {};

  const short* b00p = &Bh[(size_t)(C0 + lr) * K + lk * 8];
  const short* b10p = &Bh[(size_t)(C0 + 16 + lr) * K + lk * 8];

  bf16x8 bc[4];
  bc[0] = *(const bf16x8*)(b00p);
  bc[1] = *(const bf16x8*)(b10p);
  bc[2] = *(const bf16x8*)(b00p + 32);
  bc[3] = *(const bf16x8*)(b10p + 32);

  for (int k0 = 0; k0 < K; k0 += 64) {
    {
      const short* src = &A[(size_t)(i0 + arow) * K + k0 + aseg];
      *(us8*)&As[arow][aseg] = *(const us8*)(src);
    }
    bf16x8 bn[4];
    {
      int kn = (k0 + 64 < K) ? (k0 + 64) : k0;
      bn[0] = *(const bf16x8*)(b00p + kn);
      bn[1] = *(const bf16x8*)(b10p + kn);
      bn[2] = *(const bf16x8*)(b00p + kn + 32);
      bn[3] = *(const bf16x8*)(b10p + kn + 32);
    }
    __syncthreads();
    #pragma unroll
    for (int kc = 0; kc < 64; kc += 32) {
      bf16x8 a0 = *(const bf16x8*)&As[R0 + lr][kc + lk * 8];
      bf16x8 b0 = bc[(kc >> 5) * 2 + 0];
      bf16x8 b1 = bc[(kc >> 5) * 2 + 1];
      acc[0] = __builtin_amdgcn_mfma_f32_16x16x32_bf16(a0, b0, acc[0], 0, 0, 0);
      acc[1] = __builtin_amdgcn_mfma_f32_16x16x32_bf16(a0, b1, acc[1], 0, 0, 0);
    }
    bc[0] = bn[0]; bc[1] = bn[1]; bc[2] = bn[2]; bc[3] = bn[3];
    __syncthreads();
  }

  // epilogue: D row = lk*4+reg (n), col = lr (o); write hT[o][n] bf16 (8B st)
  #pragma unroll
  for (int fb = 0; fb < 2; ++fb) {
    int col  = c0 + C0 + fb * 16 + lr;
    int rowb = i0 + R0 + lk * 4;
    us4 pk;
    #pragma unroll
    for (int reg = 0; reg < 4; ++reg) pk[reg] = f2bf(acc[fb][reg]);
    *(us4*)&Hh[(size_t)col * M + rowb] = pk;
  }
}

// ---------------------------------------------------------------------------
// wa[h][0][k], wa[h][1][k] = sum_o W[h][k][o]*a[h][o or F+o]  (fp32 exact)
// ---------------------------------------------------------------------------
template<int F>
__global__ __launch_bounds__(256) void wa_kernel(
    const float* __restrict__ W, const float* __restrict__ a,
    float* __restrict__ wa) {
  const int gid  = blockIdx.x * 4 + (threadIdx.x >> 6);
  const int lane = threadIdx.x & 63;
  const int h = gid >> 9;
  const int k = gid & 511;
  const float* wrow = W + ((size_t)h * 512 + k) * F;
  const float* ah = a + h * 2 * F;
  float v1 = 0.f, v2 = 0.f;
  #pragma unroll
  for (int o = lane; o < F; o += 64) {
    float wv = wrow[o];
    v1 += wv * ah[o];
    v2 += wv * ah[F + o];
  }
  #pragma unroll
  for (int off = 32; off; off >>= 1) {
    v1 += __shfl_xor(v1, off);
    v2 += __shfl_xor(v2, off);
  }
  if (lane == 0) {
    wa[((size_t)h * 2 + 0) * 512 + k] = v1;
    wa[((size_t)h * 2 + 1) * 512 + k] = v2;
  }
}

// ---------------------------------------------------------------------------
// L1 logits (all 8 heads, one pass over x) + bf16 copy of x for the GEMM.
// One wave per node. grid = 4096/4.
// ---------------------------------------------------------------------------
__global__ __launch_bounds__(256) void fidot8(
    const float* __restrict__ X, const float* __restrict__ wa,
    short* __restrict__ xbf,
    float* __restrict__ eiP, float* __restrict__ eiN,
    float* __restrict__ ejP, float* __restrict__ ejN) {
  __shared__ float sw[8192];
  for (int idx = threadIdx.x; idx < 8192; idx += 256) sw[idx] = wa[idx];
  __syncthreads();
  const int n    = blockIdx.x * 4 + (threadIdx.x >> 6);
  const int lane = threadIdx.x & 63;
  const float* xr = X + (size_t)n * 512;
  float v[16] = {};
  #pragma unroll
  for (int it = 0; it < 8; ++it) {
    int k = lane + it * 64;
    float xv = xr[k];
    xbf[(size_t)n * 512 + k] = f2bf(xv);
    #pragma unroll
    for (int hh = 0; hh < 8; ++hh) {
      v[2 * hh]     += xv * sw[(2 * hh) * 512 + k];
      v[2 * hh + 1] += xv * sw[(2 * hh + 1) * 512 + k];
    }
  }
  #pragma unroll
  for (int off = 32; off; off >>= 1)
    #pragma unroll
    for (int i = 0; i < 16; ++i) v[i] += __shfl_xor(v[i], off);
  if (lane == 0) {
    #pragma unroll
    for (int hh = 0; hh < 8; ++hh) {
      int idx = hh * NNODE + n;
      float f1 = v[2 * hh], f2 = v[2 * hh + 1];
      eiP[idx] = __expf(f1); eiN[idx] = __expf(0.2f * f1);
      ejP[idx] = __expf(f2); ejN[idx] = __expf(0.2f * f2);
    }
  }
}

// ---------------------------------------------------------------------------
// PV split-j with MFMA. p = bit ? fmax(eiP_i*ejP_j, eiN_i*ejN_j) : 0
// 128-row block: wave owns 32 i-rows = 2 A-frags; every B-fragment LDS read
// feeds 2 MFMAs (halves LDS-pipe pressure per MFMA). Row-sums via MFMA with
// ones B-frag. Partial numerator stored bf16.
// grid = (NNODE/128, NCHUNK, NH)
// ---------------------------------------------------------------------------
template<int OT, int JLEN>
__global__ __launch_bounds__(256) void pv_split(
    const short* __restrict__ hT,
    const float* __restrict__ eiP, const float* __restrict__ eiN,
    const float* __restrict__ ejP, const float* __restrict__ ejN,
    const unsigned long long* __restrict__ mask,
    short* __restrict__ pnum, float* __restrict__ pl, int Fh) {
  __shared__ short hTl[OT][64][72];     // [ot][o-col][j] bf16
  __shared__ float ejPL[64], ejNL[64];

  const int t      = threadIdx.x;
  const int lane   = t & 63;
  const int w      = t >> 6;
  const int i0     = blockIdx.x * 128;
  const int chunk  = blockIdx.y;
  const int nchunk = gridDim.y;
  const int h      = blockIdx.z;
  const int hN     = h * NNODE;
  const short* hTs = hT + (size_t)h * Fh * NNODE;

  const int lr = lane & 15;
  const int lk = lane >> 4;
  const int r0 = i0 + w * 32 + lr;          // A-frag0 row
  const int r1 = r0 + 16;                   // A-frag1 row
  const float eiPr0 = eiP[hN + r0], eiNr0 = eiN[hN + r0];
  const float eiPr1 = eiP[hN + r1], eiNr1 = eiN[hN + r1];
  const unsigned long long* mrow0 = mask + (size_t)r0 * (NNODE / 64);
  const unsigned long long* mrow1 = mask + (size_t)r1 * (NNODE / 64);

  us8 onesu;
  #pragma unroll
  for (int e = 0; e < 8; ++e) onesu[e] = 0x3F80;   // bf16 1.0
  const bf16x8 ones = __builtin_bit_cast(bf16x8, onesu);

  f32x4 acc[OT][2][4] = {};
  f32x4 accL[2] = {};

  const int jbase = chunk * JLEN;
  for (int jt = 0; jt < JLEN; jt += 64) {
    const int j0 = jbase + jt;
    // stage hT tiles + per-j exp vectors
    {
      const int o = t >> 2, seg = t & 3;
      #pragma unroll
      for (int ot = 0; ot < OT; ++ot) {
        const short* src = hTs + (size_t)(ot * 64 + o) * NNODE + j0 + seg * 16;
        float4 v0 = *(const float4*)(src);
        float4 v1 = *(const float4*)(src + 8);
        *(float4*)&hTl[ot][o][seg * 16]     = v0;
        *(float4*)&hTl[ot][o][seg * 16 + 8] = v1;
      }
    }
    if (t < 64) {
      ejPL[t] = ejP[hN + j0 + t];
      ejNL[t] = ejN[hN + j0 + t];
    }
    __syncthreads();  // S1: tiles ready

    const unsigned long long mw0 = mrow0[j0 >> 6];
    const unsigned long long mw1 = mrow1[j0 >> 6];
    #pragma unroll
    for (int kk = 0; kk < 2; ++kk) {
      const int kb = kk * 32 + lk * 8;
      float4 eP0 = *(const float4*)&ejPL[kb];
      float4 eP1 = *(const float4*)&ejPL[kb + 4];
      float4 eN0 = *(const float4*)&ejNL[kb];
      float4 eN1 = *(const float4*)&ejNL[kb + 4];
      const unsigned int mb0 = (unsigned int)(mw0 >> kb) & 0xFFu;
      const unsigned int mb1 = (unsigned int)(mw1 >> kb) & 0xFFu;
      float pj[8], qj[8];
      pj[0] = eP0.x; pj[1] = eP0.y; pj[2] = eP0.z; pj[3] = eP0.w;
      pj[4] = eP1.x; pj[5] = eP1.y; pj[6] = eP1.z; pj[7] = eP1.w;
      qj[0] = eN0.x; qj[1] = eN0.y; qj[2] = eN0.z; qj[3] = eN0.w;
      qj[4] = eN1.x; qj[5] = eN1.y; qj[6] = eN1.z; qj[7] = eN1.w;
      us8 af0, af1;
      #pragma unroll
      for (int e = 0; e < 8; ++e) {
        float p0 = fmaxf(eiPr0 * pj[e], eiNr0 * qj[e]);
        float p1 = fmaxf(eiPr1 * pj[e], eiNr1 * qj[e]);
        af0[e] = f2bf((mb0 & (1u << e)) ? p0 : 0.0f);
        af1[e] = f2bf((mb1 & (1u << e)) ? p1 : 0.0f);
      }
      bf16x8 a0 = __builtin_bit_cast(bf16x8, af0);
      bf16x8 a1 = __builtin_bit_cast(bf16x8, af1);
      accL[0] = __builtin_amdgcn_mfma_f32_16x16x32_bf16(a0, ones, accL[0], 0, 0, 0);
      accL[1] = __builtin_amdgcn_mfma_f32_16x16x32_bf16(a1, ones, accL[1], 0, 0, 0);
      #pragma unroll
      for (int ot = 0; ot < OT; ++ot) {
        #pragma unroll
        for (int c = 0; c < 4; ++c) {
          bf16x8 b = *(const bf16x8*)&hTl[ot][c * 16 + lr][kb];
          acc[ot][0][c] = __builtin_amdgcn_mfma_f32_16x16x32_bf16(a0, b, acc[ot][0][c], 0, 0, 0);
          acc[ot][1][c] = __builtin_amdgcn_mfma_f32_16x16x32_bf16(a1, b, acc[ot][1][c], 0, 0, 0);
        }
      }
    }
    __syncthreads();  // S2: reads done before next stage
  }

  // pl: D row = fa*16 + lk*4 + reg within the wave's 32 rows; lr==0 lanes
  if (lr == 0) {
    #pragma unroll
    for (int fa = 0; fa < 2; ++fa)
      #pragma unroll
      for (int reg = 0; reg < 4; ++reg)
        pl[(size_t)(h * nchunk + chunk) * NNODE + i0 + w * 32 + fa * 16 + lk * 4 + reg] =
            accL[fa][reg];
  }

  // numerator (bf16): row = w*32 + fa*16 + lk*4 + reg, col = ot*64 + c*16 + lr
  short* pout = pnum + ((size_t)(h * nchunk + chunk) * NNODE + i0) * (OT * 64);
  #pragma unroll
  for (int ot = 0; ot < OT; ++ot) {
    #pragma unroll
    for (int fa = 0; fa < 2; ++fa) {
      #pragma unroll
      for (int c = 0; c < 4; ++c) {
        #pragma unroll
        for (int reg = 0; reg < 4; ++reg) {
          int row = w * 32 + fa * 16 + lk * 4 + reg;
          int col = ot * 64 + c * 16 + lr;
          pout[(size_t)row * (OT * 64) + col] = f2bf(acc[ot][fa][c][reg]);
        }
      }
    }
  }
}

// ---------------------------------------------------------------------------
// combine L1 (-> bf16 xcat) + fused L2 logit dots (fp32 exact). NC=4 chunks.
// grid = NNODE, 256 thr.
// ---------------------------------------------------------------------------
__global__ __launch_bounds__(256) void combine1_fidot(
    const short* __restrict__ pnum, const float* __restrict__ pl,
    const float* __restrict__ wa2, short* __restrict__ xcatbf,
    float* __restrict__ eiP2, float* __restrict__ eiN2,
    float* __restrict__ ejP2, float* __restrict__ ejN2) {
  const int n = blockIdx.x, t = threadIdx.x;
  float d1 = 0.f, d2 = 0.f;
  #pragma unroll
  for (int rep = 0; rep < 2; ++rep) {
    int col = t + rep * 256;
    int h = col >> 6, o = col & 63;
    float s = 0.f, L = 0.f;
    #pragma unroll
    for (int c = 0; c < 4; ++c) {
      s += bf2f((unsigned short)pnum[((size_t)(h * 4 + c) * NNODE + n) * 64 + o]);
      L += pl[(size_t)(h * 4 + c) * NNODE + n];
    }
    float xv = s / L;
    xcatbf[(size_t)n * 512 + col] = f2bf(xv);
    d1 += xv * wa2[col];
    d2 += xv * wa2[512 + col];
  }
  #pragma unroll
  for (int off = 32; off; off >>= 1) {
    d1 += __shfl_xor(d1, off);
    d2 += __shfl_xor(d2, off);
  }
  __shared__ float red[2][4];
  if ((t & 63) == 0) { red[0][t >> 6] = d1; red[1][t >> 6] = d2; }
  __syncthreads();
  if (t == 0) {
    float f1 = red[0][0] + red[0][1] + red[0][2] + red[0][3];
    float f2 = red[1][0] + red[1][1] + red[1][2] + red[1][3];
    eiP2[n] = __expf(f1); eiN2[n] = __expf(0.2f * f1);
    ejP2[n] = __expf(f2); ejN2[n] = __expf(0.2f * f2);
  }
}

// ---------------------------------------------------------------------------
// combine L2 (16 chunks) + elu + log_softmax. grid = NNODE, 128 thr.
// ---------------------------------------------------------------------------
__global__ __launch_bounds__(128) void combine2_final(
    const short* __restrict__ pnum, const float* __restrict__ pl,
    float* __restrict__ dout) {
  const int n = blockIdx.x, t = threadIdx.x;
  float s = 0.f, L = 0.f;
  #pragma unroll
  for (int c = 0; c < 16; ++c) {
    s += bf2f((unsigned short)pnum[((size_t)c * NNODE + n) * 128 + t]);
    L += pl[(size_t)c * NNODE + n];
  }
  float v = s / L;
  float e = v > 0.f ? v : (__expf(v) - 1.0f);
  float mx = e;
  #pragma unroll
  for (int off = 32; off; off >>= 1) mx = fmaxf(mx, __shfl_xor(mx, off));
  __shared__ float r2[2];
  if ((t & 63) == 0) r2[t >> 6] = mx;
  __syncthreads();
  mx = fmaxf(r2[0], r2[1]);
  float sm = __expf(e - mx);
  #pragma unroll
  for (int off = 32; off; off >>= 1) sm += __shfl_xor(sm, off);
  __shared__ float s2[2];
  if ((t & 63) == 0) s2[t >> 6] = sm;
  __syncthreads();
  float sum = s2[0] + s2[1];
  dout[(size_t)n * 128 + t] = e - mx - __logf(sum);
}

// ---------------------------------------------------------------------------
// Workspace (floats): mask .5M | xbf 1M | xcatbf 1M | hT 1M | pnum(bf16) 4.19M |
// pl .13M | Wt1 .13M | Wt2 32K | wa 9K | exps .15M.  Peak ~33 MB.
// ---------------------------------------------------------------------------
extern "C" void kernel_launch(void* const* d_in, const int* in_sizes, int n_in,
                              void* d_out, int out_size, void* d_ws, size_t ws_size,
                              hipStream_t stream) {
  const float* x     = (const float*)d_in[0];
  const int*   adj   = (const int*)d_in[1];
  const float* W     = (const float*)d_in[2];
  const float* a     = (const float*)d_in[3];
  const float* W_out = (const float*)d_in[4];
  const float* a_out = (const float*)d_in[5];
  float* out = (float*)d_out;

  float* ws = (float*)d_ws;
  unsigned long long* mask = (unsigned long long*)ws;   // 524288 f
  short* xbf    = (short*)(ws + 524288);     // 2,097,152 sh
  short* xcatbf = xbf + 2097152;             // 2,097,152 sh
  short* hT     = xcatbf + 2097152;          // 2,097,152 sh
  short* pnum   = hT + 2097152;              // 8,388,608 sh (bf16)
  float* pl   = (float*)(pnum + 8388608);    // 131,072 f
  short* Wt1  = (short*)(pl + 131072);       // 262,144 sh
  short* Wt2  = Wt1 + 262144;                // 65,536 sh
  float* wa1  = (float*)(Wt2 + 65536);       // 8,192 f
  float* wa2  = wa1 + 8192;                  // 1,024 f
  float* eiP1 = wa2 + 1024;
  float* eiN1 = eiP1 + 32768;
  float* ejP1 = eiN1 + 32768;
  float* ejN1 = ejP1 + 32768;
  float* eiP2 = ejN1 + 32768;
  float* eiN2 = eiP2 + 4096;
  float* ejP2 = eiN2 + 4096;
  float* ejN2 = ejP2 + 4096;

  packadj<<<dim3(NNODE * NNODE / 64 / 4), 256, 0, stream>>>(adj, mask);
  transpose_bf16<<<dim3(8, 1, 8), 256, 0, stream>>>(W, Wt1, 512, 64);
  transpose_bf16<<<dim3(8, 2, 1), 256, 0, stream>>>(W_out, Wt2, 512, 128);
  wa_kernel<64><<<dim3(8 * 512 / 4), 256, 0, stream>>>(W, a, wa1);
  wa_kernel<128><<<dim3(512 / 4), 256, 0, stream>>>(W_out, a_out, wa2);

  // ---- layer 1 ----
  fidot8<<<dim3(4096 / 4), 256, 0, stream>>>(x, wa1, xbf, eiP1, eiN1, ejP1, ejN1);
  gemm_mfma<<<dim3(128, 1, 8), 256, 0, stream>>>(xbf, Wt1, hT, 4096, 512, 64);
  pv_split<1, 1024><<<dim3(32, 4, 8), 256, 0, stream>>>(hT, eiP1, eiN1, ejP1, ejN1, mask, pnum, pl, 64);
  combine1_fidot<<<dim3(NNODE), 256, 0, stream>>>(pnum, pl, wa2, xcatbf, eiP2, eiN2, ejP2, ejN2);

  // ---- layer 2 ----
  gemm_mfma<<<dim3(128, 2, 1), 256, 0, stream>>>(xcatbf, Wt2, hT, 4096, 512, 128);
  pv_split<2, 256><<<dim3(32, 16, 1), 256, 0, stream>>>(hT, eiP2, eiN2, ejP2, ejN2, mask, pnum, pl, 128);
  combine2_final<<<dim3(NNODE), 128, 0, stream>>>(pnum, pl, out);
}